// Round 1
// baseline (59814.594 us; speedup 1.0000x reference)
//
#include <hip/hip_runtime.h>
#include <cstddef>

// ---------------------------------------------------------------------------
// Fused 2-layer LSTM + MLP classifier, persistent-kernel design for MI355X.
//
//   B=256, T=1000, F=64, H1=256, H2=128, MLP 128->5. All fp32 (no fp32 MFMA
//   on CDNA4 -> vector-ALU FMAs).
//
// 256 blocks x 256 threads, 1 block/CU. 4 independent batch-partitions of 64
// (lane = batch). Per partition: 32 LSTM1 blocks (8 hidden units each) +
// 32 LSTM2 blocks (4 units each), 1 hand-rolled barrier per timestep.
// LSTM2 trails LSTM1 by one step so one barrier covers both layers.
// Weights cached in LDS (uniform ds_read_b128 per 4 FMAs); h-state exchanged
// via global [k][b] buffers (lane=b coalesced), double-buffered.
// ---------------------------------------------------------------------------

#define TT    1000
#define BATCH 256
#define FF    64
#define HH1   256
#define HH2   128
#define NCLS  5
#define DMLP  128
#define NPART 4
#define PB    64
#define BPP   64   // blocks per partition
#define NTHR  256

#define SMEM_FLOATS 14432
// L1 block: sX[0..4159] = [64][65], sW[4160..14399] = [32 rows][320], sB[14400..14431]
// L2 block: sW2[0..6143] = [16 rows][384], sB2[6144..6159]; MLP reuse: sZ[0..8319] = [128][65]

__device__ __forceinline__ float sigmoidf_(float x) {
  return 1.0f / (1.0f + __expf(-x));
}
__device__ __forceinline__ float tanhf_(float x) {
  float e = __expf(-2.0f * fabsf(x));   // stable for large |x|
  float r = (1.0f - e) / (1.0f + e);
  return copysignf(r, x);
}

// Partition-local barrier. __syncthreads before arrival => every thread's
// reads AND writes of this iteration are done before any peer can advance,
// so double-buffered state needs only this one barrier per step.
// __threadfence (agent scope) gives cross-XCD release/acquire.
__device__ __forceinline__ void pbarrier(unsigned* ctr, unsigned target) {
  __threadfence();          // release: drain + make our stores agent-visible
  __syncthreads();          // all threads of block fenced before we signal
  if (threadIdx.x == 0) {
    __hip_atomic_fetch_add(ctr, 1u, __ATOMIC_RELAXED, __HIP_MEMORY_SCOPE_AGENT);
    while (__hip_atomic_load(ctr, __ATOMIC_RELAXED, __HIP_MEMORY_SCOPE_AGENT) < target) {
    }
  }
  __syncthreads();
  __threadfence();          // acquire: invalidate caches before reading peers' data
}

__launch_bounds__(NTHR, 2)
__global__ void lstm_cls_kernel(
    const float* __restrict__ x,
    const float* __restrict__ Wih1, const float* __restrict__ Whh1,
    const float* __restrict__ bih1, const float* __restrict__ bhh1,
    const float* __restrict__ Wih2, const float* __restrict__ Whh2,
    const float* __restrict__ bih2, const float* __restrict__ bhh2,
    const float* __restrict__ W1, const float* __restrict__ b1,
    const float* __restrict__ W2, const float* __restrict__ b2,
    float* __restrict__ out,
    float* __restrict__ h1buf,    // [2][HH1][BATCH]
    float* __restrict__ h2buf,    // [2][HH2][BATCH]
    unsigned* __restrict__ ctrbase) {

  __shared__ float smem[SMEM_FLOATS];

  const int tid  = threadIdx.x;
  const int w    = tid >> 6;          // wave id 0..3
  const int lane = tid & 63;
  const int part = blockIdx.x & 3;    // partition = interleaved -> spreads over XCDs
  const int rid  = blockIdx.x >> 2;   // role id 0..63 within partition
  const int gb   = part * PB + lane;  // this lane's global batch index
  unsigned* ctr  = ctrbase + part * 64;   // 256B-separated counters

  if (rid < 32) {
    // ================= LSTM1 block: owns hidden units j0..j0+7 =================
    float* sX = smem;            // x slice transposed: [k=64][b=64] pad 65
    float* sW = smem + 4160;     // [unit_local*4+gate][320]  (k: 0..63 Wih | 64..319 Whh)
    float* sB = smem + 14400;    // combined bias [unit_local*4+gate]
    const int j0 = rid * 8;

    for (int idx = tid; idx < 8 * 4 * 320; idx += NTHR) {
      int u = idx / 1280, rem = idx % 1280;
      int g = rem / 320, k = rem % 320;
      int row = g * HH1 + (j0 + u);
      sW[idx] = (k < FF) ? Wih1[row * FF + k] : Whh1[row * HH1 + (k - FF)];
    }
    if (tid < 32) {
      int u = tid >> 2, g = tid & 3;
      int row = g * HH1 + (j0 + u);
      sB[tid] = bih1[row] + bhh1[row];
    }
    __syncthreads();

    float c0 = 0.f, c1v = 0.f;      // cell state for the wave's 2 units (lane=b)
    float acc[8];
    float oA[32], oB[32];

#define FMA8_L1(OPND, TIDX)                                                    \
    {                                                                          \
      const int kw_ = (TIDX) * 32;                                             \
      _Pragma("unroll")                                                        \
      for (int u_ = 0; u_ < 2; ++u_) {                                         \
        _Pragma("unroll")                                                      \
        for (int g_ = 0; g_ < 4; ++g_) {                                       \
          const float* wr_ = &sW[((2 * w + u_) * 4 + g_) * 320 + kw_];         \
          float a_ = acc[u_ * 4 + g_];                                         \
          _Pragma("unroll")                                                    \
          for (int k_ = 0; k_ < 32; ++k_)                                      \
            a_ = __builtin_fmaf(wr_[k_], (OPND)[k_], a_);                      \
          acc[u_ * 4 + g_] = a_;                                               \
        }                                                                      \
      }                                                                        \
    }

#define LOADH_L1(OPND, KB)                                                     \
    _Pragma("unroll")                                                          \
    for (int k_ = 0; k_ < 32; ++k_)                                            \
      (OPND)[k_] = h1p[(size_t)((KB) + k_) * BATCH + gb];

    for (int i = 0; i <= TT; ++i) {
      if (i < TT) {
        // stage x[:, i, :] transposed -> sX[k][b] (global reads coalesced on k)
        #pragma unroll
        for (int r = 0; r < 16; ++r) {
          int bl = w * 16 + r;
          sX[lane * 65 + bl] = x[((size_t)(part * PB + bl) * TT + i) * FF + lane];
        }
        __syncthreads();

        const float* h1p = h1buf + ((size_t)((i + 1) & 1)) * HH1 * BATCH;  // h1[t-1]
        #pragma unroll
        for (int q = 0; q < 8; ++q) acc[q] = sB[(2 * w + (q >> 2)) * 4 + (q & 3)];

        // K = [x(64) | h1(256)], tiles of 32, ping-pong register prefetch
        #pragma unroll
        for (int k_ = 0; k_ < 32; ++k_) oA[k_] = sX[k_ * 65 + lane];
        #pragma unroll
        for (int k_ = 0; k_ < 32; ++k_) oB[k_] = sX[(32 + k_) * 65 + lane];

        FMA8_L1(oA, 0); LOADH_L1(oA, 0);
        FMA8_L1(oB, 1); LOADH_L1(oB, 32);
        FMA8_L1(oA, 2); LOADH_L1(oA, 64);
        FMA8_L1(oB, 3); LOADH_L1(oB, 96);
        FMA8_L1(oA, 4); LOADH_L1(oA, 128);
        FMA8_L1(oB, 5); LOADH_L1(oB, 160);
        FMA8_L1(oA, 6); LOADH_L1(oA, 192);
        FMA8_L1(oB, 7); LOADH_L1(oB, 224);
        FMA8_L1(oA, 8);
        FMA8_L1(oB, 9);

        float* h1w = h1buf + ((size_t)(i & 1)) * HH1 * BATCH;
        {
          float ig = sigmoidf_(acc[0]), fg = sigmoidf_(acc[1]);
          float gg = tanhf_(acc[2]),    og = sigmoidf_(acc[3]);
          c0 = fg * c0 + ig * gg;
          h1w[(size_t)(j0 + 2 * w + 0) * BATCH + gb] = og * tanhf_(c0);
          ig = sigmoidf_(acc[4]); fg = sigmoidf_(acc[5]);
          gg = tanhf_(acc[6]);    og = sigmoidf_(acc[7]);
          c1v = fg * c1v + ig * gg;
          h1w[(size_t)(j0 + 2 * w + 1) * BATCH + gb] = og * tanhf_(c1v);
        }
      }
      pbarrier(ctr, (unsigned)(i + 1) * BPP);
    }
#undef FMA8_L1
#undef LOADH_L1

  } else {
    // ================ LSTM2 block: owns hidden units u0..u0+3 (1/wave) ===========
    // Runs one step behind LSTM1: at iteration i computes t2 = i-1.
    float* sW2 = smem;           // [unit_local*4+gate][384] (k: 0..255 Wih2 | 256..383 Whh2)
    float* sB2 = smem + 6144;
    const int u0 = (rid - 32) * 4;

    for (int idx = tid; idx < 4 * 4 * 384; idx += NTHR) {
      int u = idx / 1536, rem = idx % 1536;
      int g = rem / 384, k = rem % 384;
      int row = g * HH2 + (u0 + u);
      sW2[idx] = (k < HH1) ? Wih2[row * HH1 + k] : Whh2[row * HH2 + (k - HH1)];
    }
    if (tid < 16) {
      int u = tid >> 2, g = tid & 3;
      int row = g * HH2 + (u0 + u);
      sB2[tid] = bih2[row] + bhh2[row];
    }
    __syncthreads();

    const int j = u0 + w;
    float c2 = 0.f;
    float acc[4];
    float oA[32], oB[32];

#define FMA4_L2(OPND, TIDX)                                                    \
    {                                                                          \
      const int kw_ = (TIDX) * 32;                                             \
      _Pragma("unroll")                                                        \
      for (int g_ = 0; g_ < 4; ++g_) {                                         \
        const float* wr_ = &sW2[(w * 4 + g_) * 384 + kw_];                     \
        float a_ = acc[g_];                                                    \
        _Pragma("unroll")                                                      \
        for (int k_ = 0; k_ < 32; ++k_)                                        \
          a_ = __builtin_fmaf(wr_[k_], (OPND)[k_], a_);                        \
        acc[g_] = a_;                                                          \
      }                                                                        \
    }

#define LOAD32(OPND, SRC, KB)                                                  \
    _Pragma("unroll")                                                          \
    for (int k_ = 0; k_ < 32; ++k_)                                            \
      (OPND)[k_] = (SRC)[(size_t)((KB) + k_) * BATCH + gb];

    for (int i = 0; i <= TT; ++i) {
      if (i >= 1) {
        const float* h1c = h1buf + ((size_t)((i - 1) & 1)) * HH1 * BATCH; // h1[t2]
        const float* h2p = h2buf + ((size_t)(i & 1)) * HH2 * BATCH;       // h2[t2-1]
        #pragma unroll
        for (int q = 0; q < 4; ++q) acc[q] = sB2[w * 4 + q];

        // K = [h1(256) | h2(128)], 12 tiles of 32
        LOAD32(oA, h1c, 0); LOAD32(oB, h1c, 32);
        FMA4_L2(oA, 0);  LOAD32(oA, h1c, 64);
        FMA4_L2(oB, 1);  LOAD32(oB, h1c, 96);
        FMA4_L2(oA, 2);  LOAD32(oA, h1c, 128);
        FMA4_L2(oB, 3);  LOAD32(oB, h1c, 160);
        FMA4_L2(oA, 4);  LOAD32(oA, h1c, 192);
        FMA4_L2(oB, 5);  LOAD32(oB, h1c, 224);
        FMA4_L2(oA, 6);  LOAD32(oA, h2p, 0);
        FMA4_L2(oB, 7);  LOAD32(oB, h2p, 32);
        FMA4_L2(oA, 8);  LOAD32(oA, h2p, 64);
        FMA4_L2(oB, 9);  LOAD32(oB, h2p, 96);
        FMA4_L2(oA, 10);
        FMA4_L2(oB, 11);

        float ig = sigmoidf_(acc[0]), fg = sigmoidf_(acc[1]);
        float gg = tanhf_(acc[2]),    og = sigmoidf_(acc[3]);
        c2 = fg * c2 + ig * gg;
        float* h2w = h2buf + ((size_t)((i - 1) & 1)) * HH2 * BATCH;
        h2w[(size_t)j * BATCH + gb] = og * tanhf_(c2);
      }
      pbarrier(ctr, (unsigned)(i + 1) * BPP);
    }
#undef FMA4_L2
#undef LOAD32

    if (rid == 32) {
      // ===== MLP head for this partition's 64 batch rows =====
      const float* hf = h2buf + ((size_t)((TT - 1) & 1)) * HH2 * BATCH;  // h2[T-1]
      float hreg[HH2];
      #pragma unroll
      for (int k = 0; k < HH2; ++k) hreg[k] = hf[(size_t)k * BATCH + gb];

      float* sZ = smem;          // reuse LDS: z[d][b] pad 65
      __syncthreads();           // everyone past the loop before overwriting sW2
      for (int dd = 0; dd < 32; ++dd) {
        int d = w * 32 + dd;
        float a = b1[d];
        #pragma unroll
        for (int k = 0; k < HH2; ++k)
          a = __builtin_fmaf(W1[d * HH2 + k], hreg[k], a);
        sZ[d * 65 + lane] = fmaxf(a, 0.f);
      }
      __syncthreads();
      if (w == 0) {
        #pragma unroll
        for (int c = 0; c < NCLS; ++c) {
          float a = b2[c];
          for (int d = 0; d < DMLP; ++d)
            a = __builtin_fmaf(W2[c * DMLP + d], sZ[d * 65 + lane], a);
          out[(size_t)gb * NCLS + c] = a;
        }
      }
    }
  }
}

extern "C" void kernel_launch(void* const* d_in, const int* in_sizes, int n_in,
                              void* d_out, int out_size, void* d_ws, size_t ws_size,
                              hipStream_t stream) {
  (void)in_sizes; (void)n_in; (void)out_size; (void)ws_size;

  const float* xx   = (const float*)d_in[0];
  const float* Wih1 = (const float*)d_in[1];
  const float* Whh1 = (const float*)d_in[2];
  const float* bih1 = (const float*)d_in[3];
  const float* bhh1 = (const float*)d_in[4];
  const float* Wih2 = (const float*)d_in[5];
  const float* Whh2 = (const float*)d_in[6];
  const float* bih2 = (const float*)d_in[7];
  const float* bhh2 = (const float*)d_in[8];
  const float* W1   = (const float*)d_in[9];
  const float* b1   = (const float*)d_in[10];
  const float* W2   = (const float*)d_in[11];
  const float* b2   = (const float*)d_in[12];

  float*    h1buf = (float*)d_ws;                       // 2*256*256 f32 = 512 KB
  float*    h2buf = h1buf + 2 * HH1 * BATCH;            // 2*128*256 f32 = 256 KB
  unsigned* ctr   = (unsigned*)(h2buf + 2 * HH2 * BATCH);

  size_t zero_bytes = (size_t)(2 * HH1 * BATCH + 2 * HH2 * BATCH) * sizeof(float)
                    + (size_t)NPART * 64 * sizeof(unsigned);
  hipMemsetAsync(d_ws, 0, zero_bytes, stream);          // h buffers + barrier ctrs

  hipLaunchKernelGGL(lstm_cls_kernel, dim3(NPART * BPP), dim3(NTHR), 0, stream,
                     xx, Wih1, Whh1, bih1, bhh1, Wih2, Whh2, bih2, bhh2,
                     W1, b1, W2, b2, (float*)d_out, h1buf, h2buf, ctr);
}

// Round 2
// 32417.853 us; speedup vs baseline: 1.8451x; 1.8451x over previous
//
#include <hip/hip_runtime.h>
#include <cstddef>

// ---------------------------------------------------------------------------
// Fused 2-layer LSTM + MLP classifier, persistent-kernel design for MI355X.
//
// Round 2: fence-free cross-block h-state exchange.
//   - All h-state traffic uses relaxed AGENT-scope atomics (sc0/sc1 -> MALL,
//     the device-coherent point). No __threadfence -> no buffer_wbl2/inv.
//   - Barrier: vmcnt(0) + syncthreads + relaxed atomicAdd on a counter line,
//     last arriver writes a separate flag line; others spin on the flag
//     (read-only line) with s_sleep backoff.
//   - LSTM2 consolidated to 16 blocks/partition x 8 units (same FMA shape as
//     LSTM1 blocks): 48 barrier participants, less redundant h traffic.
//   - 4-deep register operand prefetch (oA..oD) to hide MALL load latency.
// ---------------------------------------------------------------------------

#define TT    1000
#define BATCH 256
#define FF    64
#define HH1   256
#define HH2   128
#define NCLS  5
#define DMLP  128
#define NPART 4
#define PB    64
#define NROLE 48   // 32 LSTM1 blocks + 16 LSTM2 blocks per partition
#define NTHR  256

#define SMEM_FLOATS 14432
// L1 block: sX[0..4159] = [64][65], sW[4160..14399] = [32 rows][320], sB[14400..14431]
// L2 block: sW2[0..12287] = [32 rows][384], sB2[12288..12319]; MLP reuse: sZ[0..8319]

__device__ __forceinline__ float sigmoidf_(float x) {
  return 1.0f / (1.0f + __expf(-x));
}
__device__ __forceinline__ float tanhf_(float x) {
  float e = __expf(-2.0f * fabsf(x));   // stable for large |x|
  float r = (1.0f - e) / (1.0f + e);
  return copysignf(r, x);
}

#define AGLD(p)     __hip_atomic_load((p), __ATOMIC_RELAXED, __HIP_MEMORY_SCOPE_AGENT)
#define AGST(p, v)  __hip_atomic_store((p), (v), __ATOMIC_RELAXED, __HIP_MEMORY_SCOPE_AGENT)

// Partition barrier, fence-free. Preconditions: all this block's h-state
// stores were issued as agent-scope ops (they bypass L1/L2 and complete at
// the MALL). vmcnt(0) drains them; syncthreads covers all waves; then one
// relaxed agent atomicAdd. Last arriver publishes the step on a separate
// flag line; everyone else spins on that read-shared line.
__device__ __forceinline__ void pbarrier(unsigned* ctr, unsigned* flag,
                                         unsigned target) {
  asm volatile("s_waitcnt vmcnt(0)" ::: "memory");
  __syncthreads();
  if (threadIdx.x == 0) {
    unsigned old = __hip_atomic_fetch_add(ctr, 1u, __ATOMIC_RELAXED,
                                          __HIP_MEMORY_SCOPE_AGENT);
    if (old + 1u == target) {
      AGST(flag, target);
    } else {
      while (AGLD(flag) < target) __builtin_amdgcn_s_sleep(1);
    }
  }
  __syncthreads();
}

__launch_bounds__(NTHR, 1)
__global__ void lstm_cls_kernel(
    const float* __restrict__ x,
    const float* __restrict__ Wih1, const float* __restrict__ Whh1,
    const float* __restrict__ bih1, const float* __restrict__ bhh1,
    const float* __restrict__ Wih2, const float* __restrict__ Whh2,
    const float* __restrict__ bih2, const float* __restrict__ bhh2,
    const float* __restrict__ W1, const float* __restrict__ b1,
    const float* __restrict__ W2, const float* __restrict__ b2,
    float* __restrict__ out,
    float* __restrict__ h1buf,    // [2][HH1][BATCH]
    float* __restrict__ h2buf,    // [2][HH2][BATCH]
    unsigned* __restrict__ ctrbase) {

  __shared__ float smem[SMEM_FLOATS];

  const int tid  = threadIdx.x;
  const int w    = tid >> 6;          // wave id 0..3
  const int lane = tid & 63;
  const int part = blockIdx.x & 3;    // partition interleaved over XCDs
  const int rid  = blockIdx.x >> 2;   // role id 0..47 within partition
  const int gb   = part * PB + lane;  // this lane's global batch index
  unsigned* ctr  = ctrbase + part * 64;        // arrival counter line
  unsigned* flag = ctrbase + part * 64 + 32;   // flag on a separate 128B line

  if (rid < 32) {
    // ================= LSTM1 block: owns hidden units j0..j0+7 =================
    float* sX = smem;            // x slice transposed: [k=64][b=64] pad 65
    float* sW = smem + 4160;     // [unit_local*4+gate][320]  (k: 0..63 Wih | 64..319 Whh)
    float* sB = smem + 14400;
    const int j0 = rid * 8;

    for (int idx = tid; idx < 8 * 4 * 320; idx += NTHR) {
      int u = idx / 1280, rem = idx % 1280;
      int g = rem / 320, k = rem % 320;
      int row = g * HH1 + (j0 + u);
      sW[idx] = (k < FF) ? Wih1[row * FF + k] : Whh1[row * HH1 + (k - FF)];
    }
    if (tid < 32) {
      int u = tid >> 2, g = tid & 3;
      int row = g * HH1 + (j0 + u);
      sB[tid] = bih1[row] + bhh1[row];
    }
    __syncthreads();

    float c0 = 0.f, c1v = 0.f;      // cell state for the wave's 2 units (lane=b)
    float acc[8];
    float oA[32], oB[32], oC[32], oD[32];

#define FMA8_L1(OPND, TIDX)                                                    \
    {                                                                          \
      const int kw_ = (TIDX) * 32;                                             \
      _Pragma("unroll")                                                        \
      for (int u_ = 0; u_ < 2; ++u_) {                                         \
        _Pragma("unroll")                                                      \
        for (int g_ = 0; g_ < 4; ++g_) {                                       \
          const float* wr_ = &sW[((2 * w + u_) * 4 + g_) * 320 + kw_];         \
          float a_ = acc[u_ * 4 + g_];                                         \
          _Pragma("unroll")                                                    \
          for (int k_ = 0; k_ < 32; ++k_)                                      \
            a_ = __builtin_fmaf(wr_[k_], (OPND)[k_], a_);                      \
          acc[u_ * 4 + g_] = a_;                                               \
        }                                                                      \
      }                                                                        \
    }

#define LOADH_L1(OPND, KB)                                                     \
    _Pragma("unroll")                                                          \
    for (int k_ = 0; k_ < 32; ++k_)                                            \
      (OPND)[k_] = AGLD(&h1p[(size_t)((KB) + k_) * BATCH + gb]);

    for (int i = 0; i <= TT; ++i) {
      if (i < TT) {
        // stage x[:, i, :] transposed -> sX[k][b] (global reads coalesced on k)
        #pragma unroll
        for (int r = 0; r < 16; ++r) {
          int bl = w * 16 + r;
          sX[lane * 65 + bl] = x[((size_t)(part * PB + bl) * TT + i) * FF + lane];
        }
        __syncthreads();

        const float* h1p = h1buf + ((size_t)((i + 1) & 1)) * HH1 * BATCH;  // h1[t-1]
        #pragma unroll
        for (int q = 0; q < 8; ++q) acc[q] = sB[(2 * w + (q >> 2)) * 4 + (q & 3)];

        // K = [x(64) | h1(256)], tiles of 32, 4-deep rotating prefetch
        #pragma unroll
        for (int k_ = 0; k_ < 32; ++k_) oA[k_] = sX[k_ * 65 + lane];
        #pragma unroll
        for (int k_ = 0; k_ < 32; ++k_) oB[k_] = sX[(32 + k_) * 65 + lane];
        LOADH_L1(oC, 0);
        LOADH_L1(oD, 32);

        FMA8_L1(oA, 0); LOADH_L1(oA, 64);
        FMA8_L1(oB, 1); LOADH_L1(oB, 96);
        FMA8_L1(oC, 2); LOADH_L1(oC, 128);
        FMA8_L1(oD, 3); LOADH_L1(oD, 160);
        FMA8_L1(oA, 4); LOADH_L1(oA, 192);
        FMA8_L1(oB, 5); LOADH_L1(oB, 224);
        FMA8_L1(oC, 6);
        FMA8_L1(oD, 7);
        FMA8_L1(oA, 8);
        FMA8_L1(oB, 9);

        float* h1w = h1buf + ((size_t)(i & 1)) * HH1 * BATCH;
        {
          float ig = sigmoidf_(acc[0]), fg = sigmoidf_(acc[1]);
          float gg = tanhf_(acc[2]),    og = sigmoidf_(acc[3]);
          c0 = fg * c0 + ig * gg;
          AGST(&h1w[(size_t)(j0 + 2 * w + 0) * BATCH + gb], og * tanhf_(c0));
          ig = sigmoidf_(acc[4]); fg = sigmoidf_(acc[5]);
          gg = tanhf_(acc[6]);    og = sigmoidf_(acc[7]);
          c1v = fg * c1v + ig * gg;
          AGST(&h1w[(size_t)(j0 + 2 * w + 1) * BATCH + gb], og * tanhf_(c1v));
        }
      }
      pbarrier(ctr, flag, (unsigned)(i + 1) * NROLE);
    }
#undef FMA8_L1
#undef LOADH_L1

  } else {
    // ============ LSTM2 block: owns hidden units u0..u0+7 (2/wave) ============
    // Runs one step behind LSTM1: at iteration i computes t2 = i-1.
    float* sW2 = smem;           // [unit_local*4+gate][384] (k: 0..255 Wih2 | 256..383 Whh2)
    float* sB2 = smem + 12288;
    const int u0 = (rid - 32) * 8;

    for (int idx = tid; idx < 8 * 4 * 384; idx += NTHR) {
      int u = idx / 1536, rem = idx % 1536;
      int g = rem / 384, k = rem % 384;
      int row = g * HH2 + (u0 + u);
      sW2[idx] = (k < HH1) ? Wih2[row * HH1 + k] : Whh2[row * HH2 + (k - HH1)];
    }
    if (tid < 32) {
      int u = tid >> 2, g = tid & 3;
      int row = g * HH2 + (u0 + u);
      sB2[tid] = bih2[row] + bhh2[row];
    }
    __syncthreads();

    float c0 = 0.f, c1v = 0.f;
    float acc[8];
    float oA[32], oB[32], oC[32], oD[32];

#define FMA8_L2(OPND, TIDX)                                                    \
    {                                                                          \
      const int kw_ = (TIDX) * 32;                                             \
      _Pragma("unroll")                                                        \
      for (int u_ = 0; u_ < 2; ++u_) {                                         \
        _Pragma("unroll")                                                      \
        for (int g_ = 0; g_ < 4; ++g_) {                                       \
          const float* wr_ = &sW2[((2 * w + u_) * 4 + g_) * 384 + kw_];        \
          float a_ = acc[u_ * 4 + g_];                                         \
          _Pragma("unroll")                                                    \
          for (int k_ = 0; k_ < 32; ++k_)                                      \
            a_ = __builtin_fmaf(wr_[k_], (OPND)[k_], a_);                      \
          acc[u_ * 4 + g_] = a_;                                               \
        }                                                                      \
      }                                                                        \
    }

#define LOAD32(OPND, SRC, KB)                                                  \
    _Pragma("unroll")                                                          \
    for (int k_ = 0; k_ < 32; ++k_)                                            \
      (OPND)[k_] = AGLD(&(SRC)[(size_t)((KB) + k_) * BATCH + gb]);

    for (int i = 0; i <= TT; ++i) {
      if (i >= 1) {
        const float* h1c = h1buf + ((size_t)((i - 1) & 1)) * HH1 * BATCH; // h1[t2]
        const float* h2p = h2buf + ((size_t)(i & 1)) * HH2 * BATCH;       // h2[t2-1]
        #pragma unroll
        for (int q = 0; q < 8; ++q) acc[q] = sB2[(2 * w + (q >> 2)) * 4 + (q & 3)];

        // K = [h1(256) | h2(128)], 12 tiles of 32, 4-deep rotating prefetch
        LOAD32(oA, h1c, 0);
        LOAD32(oB, h1c, 32);
        LOAD32(oC, h1c, 64);
        LOAD32(oD, h1c, 96);

        FMA8_L2(oA, 0);  LOAD32(oA, h1c, 128);
        FMA8_L2(oB, 1);  LOAD32(oB, h1c, 160);
        FMA8_L2(oC, 2);  LOAD32(oC, h1c, 192);
        FMA8_L2(oD, 3);  LOAD32(oD, h1c, 224);
        FMA8_L2(oA, 4);  LOAD32(oA, h2p, 0);
        FMA8_L2(oB, 5);  LOAD32(oB, h2p, 32);
        FMA8_L2(oC, 6);  LOAD32(oC, h2p, 64);
        FMA8_L2(oD, 7);  LOAD32(oD, h2p, 96);
        FMA8_L2(oA, 8);
        FMA8_L2(oB, 9);
        FMA8_L2(oC, 10);
        FMA8_L2(oD, 11);

        float* h2w = h2buf + ((size_t)((i - 1) & 1)) * HH2 * BATCH;
        {
          float ig = sigmoidf_(acc[0]), fg = sigmoidf_(acc[1]);
          float gg = tanhf_(acc[2]),    og = sigmoidf_(acc[3]);
          c0 = fg * c0 + ig * gg;
          AGST(&h2w[(size_t)(u0 + 2 * w + 0) * BATCH + gb], og * tanhf_(c0));
          ig = sigmoidf_(acc[4]); fg = sigmoidf_(acc[5]);
          gg = tanhf_(acc[6]);    og = sigmoidf_(acc[7]);
          c1v = fg * c1v + ig * gg;
          AGST(&h2w[(size_t)(u0 + 2 * w + 1) * BATCH + gb], og * tanhf_(c1v));
        }
      }
      pbarrier(ctr, flag, (unsigned)(i + 1) * NROLE);
    }
#undef FMA8_L2
#undef LOAD32

    if (rid == 32) {
      // ===== MLP head for this partition's 64 batch rows =====
      const float* hf = h2buf + ((size_t)((TT - 1) & 1)) * HH2 * BATCH;  // h2[T-1]
      float hreg[HH2];
      #pragma unroll
      for (int k = 0; k < HH2; ++k) hreg[k] = AGLD(&hf[(size_t)k * BATCH + gb]);

      float* sZ = smem;          // reuse LDS: z[d][b] pad 65
      __syncthreads();           // everyone past the loop before overwriting sW2
      for (int dd = 0; dd < 32; ++dd) {
        int d = w * 32 + dd;
        float a = b1[d];
        #pragma unroll
        for (int k = 0; k < HH2; ++k)
          a = __builtin_fmaf(W1[d * HH2 + k], hreg[k], a);
        sZ[d * 65 + lane] = fmaxf(a, 0.f);
      }
      __syncthreads();
      if (w == 0) {
        #pragma unroll
        for (int c = 0; c < NCLS; ++c) {
          float a = b2[c];
          for (int d = 0; d < DMLP; ++d)
            a = __builtin_fmaf(W2[c * DMLP + d], sZ[d * 65 + lane], a);
          out[(size_t)gb * NCLS + c] = a;
        }
      }
    }
  }
}

extern "C" void kernel_launch(void* const* d_in, const int* in_sizes, int n_in,
                              void* d_out, int out_size, void* d_ws, size_t ws_size,
                              hipStream_t stream) {
  (void)in_sizes; (void)n_in; (void)out_size; (void)ws_size;

  const float* xx   = (const float*)d_in[0];
  const float* Wih1 = (const float*)d_in[1];
  const float* Whh1 = (const float*)d_in[2];
  const float* bih1 = (const float*)d_in[3];
  const float* bhh1 = (const float*)d_in[4];
  const float* Wih2 = (const float*)d_in[5];
  const float* Whh2 = (const float*)d_in[6];
  const float* bih2 = (const float*)d_in[7];
  const float* bhh2 = (const float*)d_in[8];
  const float* W1   = (const float*)d_in[9];
  const float* b1   = (const float*)d_in[10];
  const float* W2   = (const float*)d_in[11];
  const float* b2   = (const float*)d_in[12];

  float*    h1buf = (float*)d_ws;                       // 2*256*256 f32 = 512 KB
  float*    h2buf = h1buf + 2 * HH1 * BATCH;            // 2*128*256 f32 = 256 KB
  unsigned* ctr   = (unsigned*)(h2buf + 2 * HH2 * BATCH);

  size_t zero_bytes = (size_t)(2 * HH1 * BATCH + 2 * HH2 * BATCH) * sizeof(float)
                    + (size_t)NPART * 64 * sizeof(unsigned);
  hipMemsetAsync(d_ws, 0, zero_bytes, stream);          // h buffers + barrier ctrs/flags

  hipLaunchKernelGGL(lstm_cls_kernel, dim3(NPART * NROLE), dim3(NTHR), 0, stream,
                     xx, Wih1, Whh1, bih1, bhh1, Wih2, Whh2, bih2, bhh2,
                     W1, b1, W2, b2, (float*)d_out, h1buf, h2buf, ctr);
}

// Round 6
// 23663.387 us; speedup vs baseline: 2.5277x; 1.3700x over previous
//
#include <hip/hip_runtime.h>
#include <cstddef>

// ---------------------------------------------------------------------------
// Fused 2-layer LSTM + MLP classifier, persistent-kernel design for MI355X.
//
// Round 6 = Round 4/5 resubmission (both rounds: GPU acquisition timeout,
// kernel never ran).
//   r2 lesson: per-element __hip_atomic_load (agent scope) exposed ~200cy of
//   L2-hit latency PER LOAD (384 loads/lane/step ~= 32us/step = measured).
//   Fix: stage the whole h-state per block per step into LDS with inline-asm
//   global_load_dwordx4 sc0 sc1 (coherence bits proven correct in r2),
//   issued back-to-back + ONE operand-free s_waitcnt vmcnt(0) ("memory"
//   clobber + sched_barrier(0) pin the order), ds_write_b128, one
//   __syncthreads. Latency exposure: ~1 RT/step instead of ~350.
//
//   - 8 partitions x 32 samples (bid&7 -> partition; 24 blocks/partition:
//     16 LSTM1 blocks x 16 units + 8 LSTM2 blocks x 16 units).
//   - lane: s = lane&31 (sample), uh = lane>>5 (unit-half); each lane owns
//     2 units x 4 gates (acc[8]); weights in LDS, read as float4 (b128,
//     2-addr/wave = cheap broadcast).
//   - Dynamic LDS 147.7KB (hipFuncSetAttribute), 1 block/CU, 192 blocks.
//   - Barrier: r2's proven atomicAdd+flag (agent, relaxed) per partition.
// ---------------------------------------------------------------------------

#define TT    1000
#define BATCH 256
#define FF    64
#define HH1   256
#define HH2   128
#define NCLS  5
#define DMLP  128
#define NPART 8
#define PB    32
#define NROLE 24
#define NTHR  256

#define SMEM_FLOATS 36928
#define SMEM_BYTES  (SMEM_FLOATS * 4)

// LDS float offsets (union of the two roles)
#define L1_W   0        // [64 rows][320] = 20480
#define L1_H1  20480    // [256][32] = 8192
#define L1_X   28672    // [64][33]  = 2112
#define L1_B   30784    // 64
#define L2_W   0        // [64 rows][384] = 24576
#define L2_H1  24576    // 8192
#define L2_H2  32768    // [128][32] = 4096
#define L2_B   36864    // 64
// MLP reuse: smem[0..4095] = h2 final [128][32]; smem[4096..8319] = z[128][33]

__device__ __forceinline__ float sigmoidf_(float x) {
  return 1.0f / (1.0f + __expf(-x));
}
__device__ __forceinline__ float tanhf_(float x) {
  float e = __expf(-2.0f * fabsf(x));   // stable for large |x|
  float r = (1.0f - e) / (1.0f + e);
  return copysignf(r, x);
}

#define AGLD(p)     __hip_atomic_load((p), __ATOMIC_RELAXED, __HIP_MEMORY_SCOPE_AGENT)
#define AGST(p, v)  __hip_atomic_store((p), (v), __ATOMIC_RELAXED, __HIP_MEMORY_SCOPE_AGENT)

// Coherent 16B load: bypass L1 (sc0) + device-coherent (sc1) -- same cache-op
// bits r2's __hip_atomic_load produced, but many can be in flight with a
// single waitcnt. "memory" clobber keeps surrounding mem ops ordered.
__device__ __forceinline__ void cld4(float4& r, const float* p) {
  asm volatile("global_load_dwordx4 %0, %1, off sc0 sc1"
               : "=v"(r) : "v"(p) : "memory");
}

// Drain all outstanding vector-memory ops (our asm loads included), then
// forbid the scheduler from moving anything above the wait.
__device__ __forceinline__ void vm_drain() {
  asm volatile("s_waitcnt vmcnt(0)" ::: "memory");
  __builtin_amdgcn_sched_barrier(0);
}

// Partition barrier (r2-proven). vmcnt(0) drains this block's h stores
// (write-through, device-visible); one relaxed agent atomicAdd per block;
// last arriver publishes step on a separate flag line; others spin on it.
__device__ __forceinline__ void pbarrier(unsigned* ctr, unsigned* flag,
                                         unsigned target) {
  asm volatile("s_waitcnt vmcnt(0)" ::: "memory");
  __syncthreads();
  if (threadIdx.x == 0) {
    unsigned old = __hip_atomic_fetch_add(ctr, 1u, __ATOMIC_RELAXED,
                                          __HIP_MEMORY_SCOPE_AGENT);
    if (old + 1u == target) {
      AGST(flag, target);
    } else {
      while (AGLD(flag) < target) __builtin_amdgcn_s_sleep(1);
    }
  }
  __syncthreads();
}

__launch_bounds__(NTHR, 1)
__global__ void lstm_cls_kernel(
    const float* __restrict__ x,
    const float* __restrict__ Wih1, const float* __restrict__ Whh1,
    const float* __restrict__ bih1, const float* __restrict__ bhh1,
    const float* __restrict__ Wih2, const float* __restrict__ Whh2,
    const float* __restrict__ bih2, const float* __restrict__ bhh2,
    const float* __restrict__ W1, const float* __restrict__ b1,
    const float* __restrict__ W2, const float* __restrict__ b2,
    float* __restrict__ out,
    float* __restrict__ h1buf,    // [NPART][2][HH1][PB]
    float* __restrict__ h2buf,    // [NPART][2][HH2][PB]
    unsigned* __restrict__ ctrbase) {

  extern __shared__ float smem[];

  const int tid  = threadIdx.x;
  const int w    = tid >> 6;          // wave 0..3
  const int lane = tid & 63;
  const int s    = lane & 31;         // sample within partition
  const int uh   = lane >> 5;         // unit-half 0/1
  const int part = blockIdx.x & 7;    // partition (bid&7 -> XCD-friendly)
  const int rid  = blockIdx.x >> 3;   // role 0..23
  unsigned* ctr  = ctrbase + part * 64;
  unsigned* flag = ctrbase + part * 64 + 32;

  float* h1part = h1buf + (size_t)part * 2 * HH1 * PB;   // 16384 floats
  float* h2part = h2buf + (size_t)part * 2 * HH2 * PB;   // 8192 floats

  if (rid < 16) {
    // ============ LSTM1 block: 16 units j0..j0+15 ============
    float* sW  = smem + L1_W;
    float* sh1 = smem + L1_H1;
    float* sX  = smem + L1_X;
    float* sB  = smem + L1_B;
    const int j0 = rid * 16;

    for (int idx = tid; idx < 64 * 320; idx += NTHR) {
      int ul = idx / 1280, g = (idx / 320) & 3, k = idx % 320;
      int row = g * HH1 + (j0 + ul);
      sW[idx] = (k < FF) ? Wih1[row * FF + k] : Whh1[row * HH1 + (k - FF)];
    }
    if (tid < 64) {
      int ul = tid >> 2, g = tid & 3;
      int row = g * HH1 + (j0 + ul);
      sB[tid] = bih1[row] + bhh1[row];
    }
    __syncthreads();

    // lane owns units j0 + w*4 + uh*2 + {0,1}
    const float* wr[8];
    #pragma unroll
    for (int q = 0; q < 8; ++q)
      wr[q] = &sW[((w * 4 + uh * 2 + (q >> 2)) * 4 + (q & 3)) * 320];

    float cA = 0.f, cB = 0.f;

    for (int i = 0; i <= TT; ++i) {
      if (i < TT) {
        const float* h1p = h1part + ((i + 1) & 1) * (HH1 * PB);
        float4 a0, a1, a2, a3, a4, a5, a6, a7;
        cld4(a0, h1p + 0 * 1024 + tid * 4);
        cld4(a1, h1p + 1 * 1024 + tid * 4);
        cld4(a2, h1p + 2 * 1024 + tid * 4);
        cld4(a3, h1p + 3 * 1024 + tid * 4);
        cld4(a4, h1p + 4 * 1024 + tid * 4);
        cld4(a5, h1p + 5 * 1024 + tid * 4);
        cld4(a6, h1p + 6 * 1024 + tid * 4);
        cld4(a7, h1p + 7 * 1024 + tid * 4);

        // x[:, i, :] -> sX[f][bl] (f=lane, coalesced on f)
        float xv[8];
        #pragma unroll
        for (int r = 0; r < 8; ++r)
          xv[r] = x[((size_t)(part * PB + (w * 8 + r)) * TT + i) * FF + lane];
        #pragma unroll
        for (int r = 0; r < 8; ++r)
          sX[lane * 33 + (w * 8 + r)] = xv[r];

        vm_drain();
        *reinterpret_cast<float4*>(&sh1[0 * 1024 + tid * 4]) = a0;
        *reinterpret_cast<float4*>(&sh1[1 * 1024 + tid * 4]) = a1;
        *reinterpret_cast<float4*>(&sh1[2 * 1024 + tid * 4]) = a2;
        *reinterpret_cast<float4*>(&sh1[3 * 1024 + tid * 4]) = a3;
        *reinterpret_cast<float4*>(&sh1[4 * 1024 + tid * 4]) = a4;
        *reinterpret_cast<float4*>(&sh1[5 * 1024 + tid * 4]) = a5;
        *reinterpret_cast<float4*>(&sh1[6 * 1024 + tid * 4]) = a6;
        *reinterpret_cast<float4*>(&sh1[7 * 1024 + tid * 4]) = a7;
        __syncthreads();

        float acc[8];
        #pragma unroll
        for (int q = 0; q < 8; ++q)
          acc[q] = sB[(w * 4 + uh * 2 + (q >> 2)) * 4 + (q & 3)];

        #pragma unroll 4
        for (int kk = 0; kk < 64; kk += 4) {
          float o0 = sX[(kk + 0) * 33 + s], o1 = sX[(kk + 1) * 33 + s];
          float o2 = sX[(kk + 2) * 33 + s], o3 = sX[(kk + 3) * 33 + s];
          #pragma unroll
          for (int q = 0; q < 8; ++q) {
            float4 wv = *reinterpret_cast<const float4*>(wr[q] + kk);
            acc[q] = __builtin_fmaf(wv.w, o3, __builtin_fmaf(wv.z, o2,
                     __builtin_fmaf(wv.y, o1, __builtin_fmaf(wv.x, o0, acc[q]))));
          }
        }
        #pragma unroll 4
        for (int kk = 0; kk < 256; kk += 4) {
          float o0 = sh1[(kk + 0) * 32 + s], o1 = sh1[(kk + 1) * 32 + s];
          float o2 = sh1[(kk + 2) * 32 + s], o3 = sh1[(kk + 3) * 32 + s];
          #pragma unroll
          for (int q = 0; q < 8; ++q) {
            float4 wv = *reinterpret_cast<const float4*>(wr[q] + 64 + kk);
            acc[q] = __builtin_fmaf(wv.w, o3, __builtin_fmaf(wv.z, o2,
                     __builtin_fmaf(wv.y, o1, __builtin_fmaf(wv.x, o0, acc[q]))));
          }
        }

        float* h1w = h1part + (i & 1) * (HH1 * PB);
        const int ja = j0 + w * 4 + uh * 2;
        {
          float ig = sigmoidf_(acc[0]), fg = sigmoidf_(acc[1]);
          float gg = tanhf_(acc[2]),    og = sigmoidf_(acc[3]);
          cA = fg * cA + ig * gg;
          AGST(&h1w[(ja + 0) * PB + s], og * tanhf_(cA));
          ig = sigmoidf_(acc[4]); fg = sigmoidf_(acc[5]);
          gg = tanhf_(acc[6]);    og = sigmoidf_(acc[7]);
          cB = fg * cB + ig * gg;
          AGST(&h1w[(ja + 1) * PB + s], og * tanhf_(cB));
        }
      }
      pbarrier(ctr, flag, (unsigned)(i + 1) * NROLE);
    }

  } else {
    // ============ LSTM2 block: 16 units u0..u0+15; trails by 1 step ============
    float* sW2 = smem + L2_W;
    float* sh1 = smem + L2_H1;
    float* sh2 = smem + L2_H2;
    float* sB2 = smem + L2_B;
    const int u0 = (rid - 16) * 16;

    for (int idx = tid; idx < 64 * 384; idx += NTHR) {
      int ul = idx / 1536, g = (idx / 384) & 3, k = idx % 384;
      int row = g * HH2 + (u0 + ul);
      sW2[idx] = (k < HH1) ? Wih2[row * HH1 + k] : Whh2[row * HH2 + (k - HH1)];
    }
    if (tid < 64) {
      int ul = tid >> 2, g = tid & 3;
      int row = g * HH2 + (u0 + ul);
      sB2[tid] = bih2[row] + bhh2[row];
    }
    __syncthreads();

    const float* wr[8];
    #pragma unroll
    for (int q = 0; q < 8; ++q)
      wr[q] = &sW2[((w * 4 + uh * 2 + (q >> 2)) * 4 + (q & 3)) * 384];

    float cA = 0.f, cB = 0.f;

    for (int i = 0; i <= TT; ++i) {
      if (i >= 1) {
        const float* h1c = h1part + ((i - 1) & 1) * (HH1 * PB);  // h1[t2]
        const float* h2p = h2part + (i & 1) * (HH2 * PB);        // h2[t2-1]
        float4 a0, a1, a2, a3, a4, a5, a6, a7, b0v, b1v, b2v, b3v;
        cld4(a0, h1c + 0 * 1024 + tid * 4);
        cld4(a1, h1c + 1 * 1024 + tid * 4);
        cld4(a2, h1c + 2 * 1024 + tid * 4);
        cld4(a3, h1c + 3 * 1024 + tid * 4);
        cld4(a4, h1c + 4 * 1024 + tid * 4);
        cld4(a5, h1c + 5 * 1024 + tid * 4);
        cld4(a6, h1c + 6 * 1024 + tid * 4);
        cld4(a7, h1c + 7 * 1024 + tid * 4);
        cld4(b0v, h2p + 0 * 1024 + tid * 4);
        cld4(b1v, h2p + 1 * 1024 + tid * 4);
        cld4(b2v, h2p + 2 * 1024 + tid * 4);
        cld4(b3v, h2p + 3 * 1024 + tid * 4);
        vm_drain();
        *reinterpret_cast<float4*>(&sh1[0 * 1024 + tid * 4]) = a0;
        *reinterpret_cast<float4*>(&sh1[1 * 1024 + tid * 4]) = a1;
        *reinterpret_cast<float4*>(&sh1[2 * 1024 + tid * 4]) = a2;
        *reinterpret_cast<float4*>(&sh1[3 * 1024 + tid * 4]) = a3;
        *reinterpret_cast<float4*>(&sh1[4 * 1024 + tid * 4]) = a4;
        *reinterpret_cast<float4*>(&sh1[5 * 1024 + tid * 4]) = a5;
        *reinterpret_cast<float4*>(&sh1[6 * 1024 + tid * 4]) = a6;
        *reinterpret_cast<float4*>(&sh1[7 * 1024 + tid * 4]) = a7;
        *reinterpret_cast<float4*>(&sh2[0 * 1024 + tid * 4]) = b0v;
        *reinterpret_cast<float4*>(&sh2[1 * 1024 + tid * 4]) = b1v;
        *reinterpret_cast<float4*>(&sh2[2 * 1024 + tid * 4]) = b2v;
        *reinterpret_cast<float4*>(&sh2[3 * 1024 + tid * 4]) = b3v;
        __syncthreads();

        float acc[8];
        #pragma unroll
        for (int q = 0; q < 8; ++q)
          acc[q] = sB2[(w * 4 + uh * 2 + (q >> 2)) * 4 + (q & 3)];

        #pragma unroll 4
        for (int kk = 0; kk < 256; kk += 4) {
          float o0 = sh1[(kk + 0) * 32 + s], o1 = sh1[(kk + 1) * 32 + s];
          float o2 = sh1[(kk + 2) * 32 + s], o3 = sh1[(kk + 3) * 32 + s];
          #pragma unroll
          for (int q = 0; q < 8; ++q) {
            float4 wv = *reinterpret_cast<const float4*>(wr[q] + kk);
            acc[q] = __builtin_fmaf(wv.w, o3, __builtin_fmaf(wv.z, o2,
                     __builtin_fmaf(wv.y, o1, __builtin_fmaf(wv.x, o0, acc[q]))));
          }
        }
        #pragma unroll 4
        for (int kk = 0; kk < 128; kk += 4) {
          float o0 = sh2[(kk + 0) * 32 + s], o1 = sh2[(kk + 1) * 32 + s];
          float o2 = sh2[(kk + 2) * 32 + s], o3 = sh2[(kk + 3) * 32 + s];
          #pragma unroll
          for (int q = 0; q < 8; ++q) {
            float4 wv = *reinterpret_cast<const float4*>(wr[q] + 256 + kk);
            acc[q] = __builtin_fmaf(wv.w, o3, __builtin_fmaf(wv.z, o2,
                     __builtin_fmaf(wv.y, o1, __builtin_fmaf(wv.x, o0, acc[q]))));
          }
        }

        float* h2w = h2part + ((i - 1) & 1) * (HH2 * PB);
        const int ja = u0 + w * 4 + uh * 2;
        {
          float ig = sigmoidf_(acc[0]), fg = sigmoidf_(acc[1]);
          float gg = tanhf_(acc[2]),    og = sigmoidf_(acc[3]);
          cA = fg * cA + ig * gg;
          AGST(&h2w[(ja + 0) * PB + s], og * tanhf_(cA));
          ig = sigmoidf_(acc[4]); fg = sigmoidf_(acc[5]);
          gg = tanhf_(acc[6]);    og = sigmoidf_(acc[7]);
          cB = fg * cB + ig * gg;
          AGST(&h2w[(ja + 1) * PB + s], og * tanhf_(cB));
        }
      }
      pbarrier(ctr, flag, (unsigned)(i + 1) * NROLE);
    }

    if (rid == 16) {
      // ===== MLP head for this partition's 32 samples =====
      const float* hf = h2part + ((TT - 1) & 1) * (HH2 * PB);  // h2[T-1]
      float4 a0, a1, a2, a3;
      cld4(a0, hf + 0 * 1024 + tid * 4);
      cld4(a1, hf + 1 * 1024 + tid * 4);
      cld4(a2, hf + 2 * 1024 + tid * 4);
      cld4(a3, hf + 3 * 1024 + tid * 4);
      vm_drain();
      __syncthreads();   // everyone done with sW2 before reuse
      *reinterpret_cast<float4*>(&smem[0 * 1024 + tid * 4]) = a0;
      *reinterpret_cast<float4*>(&smem[1 * 1024 + tid * 4]) = a1;
      *reinterpret_cast<float4*>(&smem[2 * 1024 + tid * 4]) = a2;
      *reinterpret_cast<float4*>(&smem[3 * 1024 + tid * 4]) = a3;
      __syncthreads();

      float* sZ = smem + 4096;   // [128][33]
      const int dbase = w * 32 + uh * 16;
      for (int dd = 0; dd < 16; ++dd) {
        int d = dbase + dd;
        float a = b1[d];
        for (int k4 = 0; k4 < 32; ++k4) {
          float4 wv = *reinterpret_cast<const float4*>(&W1[d * HH2 + k4 * 4]);
          a = __builtin_fmaf(wv.x, smem[(k4 * 4 + 0) * 32 + s],
              __builtin_fmaf(wv.y, smem[(k4 * 4 + 1) * 32 + s],
              __builtin_fmaf(wv.z, smem[(k4 * 4 + 2) * 32 + s],
              __builtin_fmaf(wv.w, smem[(k4 * 4 + 3) * 32 + s], a))));
        }
        sZ[d * 33 + s] = fmaxf(a, 0.f);
      }
      __syncthreads();
      if (tid < 32) {
        #pragma unroll
        for (int c = 0; c < NCLS; ++c) {
          float a = b2[c];
          for (int d = 0; d < DMLP; ++d)
            a = __builtin_fmaf(W2[c * DMLP + d], sZ[d * 33 + tid], a);
          out[(size_t)(part * PB + tid) * NCLS + c] = a;
        }
      }
    }
  }
}

extern "C" void kernel_launch(void* const* d_in, const int* in_sizes, int n_in,
                              void* d_out, int out_size, void* d_ws, size_t ws_size,
                              hipStream_t stream) {
  (void)in_sizes; (void)n_in; (void)out_size; (void)ws_size;

  const float* xx   = (const float*)d_in[0];
  const float* Wih1 = (const float*)d_in[1];
  const float* Whh1 = (const float*)d_in[2];
  const float* bih1 = (const float*)d_in[3];
  const float* bhh1 = (const float*)d_in[4];
  const float* Wih2 = (const float*)d_in[5];
  const float* Whh2 = (const float*)d_in[6];
  const float* bih2 = (const float*)d_in[7];
  const float* bhh2 = (const float*)d_in[8];
  const float* W1   = (const float*)d_in[9];
  const float* b1   = (const float*)d_in[10];
  const float* W2   = (const float*)d_in[11];
  const float* b2   = (const float*)d_in[12];

  float*    h1buf = (float*)d_ws;                          // 8*2*256*32 f32 = 512 KB
  float*    h2buf = h1buf + (size_t)NPART * 2 * HH1 * PB;  // 8*2*128*32 f32 = 256 KB
  unsigned* ctr   = (unsigned*)(h2buf + (size_t)NPART * 2 * HH2 * PB);

  size_t zero_bytes =
      (size_t)NPART * 2 * (HH1 + HH2) * PB * sizeof(float) +
      (size_t)NPART * 64 * sizeof(unsigned);
  hipMemsetAsync(d_ws, 0, zero_bytes, stream);   // h buffers + barrier ctrs/flags

  // Host-side property set (not a stream op) -- safe under graph capture.
  (void)hipFuncSetAttribute(reinterpret_cast<const void*>(lstm_cls_kernel),
                            hipFuncAttributeMaxDynamicSharedMemorySize,
                            SMEM_BYTES);

  hipLaunchKernelGGL(lstm_cls_kernel, dim3(NPART * NROLE), dim3(NTHR),
                     SMEM_BYTES, stream,
                     xx, Wih1, Whh1, bih1, bhh1, Wih2, Whh2, bih2, bhh2,
                     W1, b1, W2, b2, (float*)d_out, h1buf, h2buf, ctr);
}

// Round 7
// 12578.123 us; speedup vs baseline: 4.7554x; 1.8813x over previous
//
#include <hip/hip_runtime.h>
#include <cstddef>

// ---------------------------------------------------------------------------
// Fused 2-layer LSTM + MLP classifier, persistent-kernel design for MI355X.
//
// Round 7: occupancy 4x (1024-thread blocks, 4 waves/SIMD).
//   r6 diagnosis: VALUBusy 21.5%, MfmaUtil 0, HBM 0.3%, Occupancy 9.25%
//   (1 wave/SIMD) -> latency-bound: ~5us/step of issue vs 23.7us measured.
//   Fix: same 192 blocks / 24-per-partition barrier, but 1024 threads:
//   wave w owns unit (rid*16+w); lane = sample(s=lane&31) x gatepair(p=lane>>5);
//   each lane 2 gate-dots (1/4 of r6 work); pre-activations exchanged with
//   __shfl_xor(.,32) (pair lanes in same wave); c/h computed redundantly.
//   Operands unified op[s][x|h1] with b128 reads; global h layout [s][unit]
//   -> transpose-free staging; strides 324/388 (16B aligned, bank-spread).
// ---------------------------------------------------------------------------

#define TT    1000
#define BATCH 256
#define FF    64
#define HH1   256
#define HH2   128
#define NCLS  5
#define DMLP  128
#define NPART 8
#define PB    32
#define NROLE 24   // 16 LSTM1 + 8 LSTM2 blocks per partition
#define NTHR  1024

#define SMEM_FLOATS 37312
#define SMEM_BYTES  (SMEM_FLOATS * 4)

// L1 LDS map (floats): W [64 rows][324] | OP [32][324] (0..64 x, 64..320 h1) | B[64]
#define L1_W   0
#define L1_OP  20736
#define L1_B   31104
// L2 LDS map: W [64 rows][388] | OP [32][388] (0..256 h1, 256..384 h2) | B[64]
#define L2_W   0
#define L2_OP  24832
#define L2_B   37248
// MLP reuse: Z0 [32][132] at 0, Z1 [128][33] at 4224

__device__ __forceinline__ float sigmoidf_(float x) {
  return 1.0f / (1.0f + __expf(-x));
}
__device__ __forceinline__ float tanhf_(float x) {
  float e = __expf(-2.0f * fabsf(x));   // stable for large |x|
  float r = (1.0f - e) / (1.0f + e);
  return copysignf(r, x);
}

#define AGLD(p)     __hip_atomic_load((p), __ATOMIC_RELAXED, __HIP_MEMORY_SCOPE_AGENT)
#define AGST(p, v)  __hip_atomic_store((p), (v), __ATOMIC_RELAXED, __HIP_MEMORY_SCOPE_AGENT)

// Coherent 16B load: bypass L1 (sc0) + device-coherent (sc1); many in flight,
// one waitcnt. "memory" clobber keeps surrounding mem ops ordered.
__device__ __forceinline__ void cld4(float4& r, const float* p) {
  asm volatile("global_load_dwordx4 %0, %1, off sc0 sc1"
               : "=v"(r) : "v"(p) : "memory");
}

__device__ __forceinline__ void vm_drain() {
  asm volatile("s_waitcnt vmcnt(0)" ::: "memory");
  __builtin_amdgcn_sched_barrier(0);
}

// Partition barrier (r2/r6-proven). vmcnt(0) drains write-through h stores;
// one relaxed agent atomicAdd per block; last arriver publishes step on a
// separate flag line; others spin on it.
__device__ __forceinline__ void pbarrier(unsigned* ctr, unsigned* flag,
                                         unsigned target) {
  asm volatile("s_waitcnt vmcnt(0)" ::: "memory");
  __syncthreads();
  if (threadIdx.x == 0) {
    unsigned old = __hip_atomic_fetch_add(ctr, 1u, __ATOMIC_RELAXED,
                                          __HIP_MEMORY_SCOPE_AGENT);
    if (old + 1u == target) {
      AGST(flag, target);
    } else {
      while (AGLD(flag) < target) __builtin_amdgcn_s_sleep(1);
    }
  }
  __syncthreads();
}

__launch_bounds__(NTHR, 1)
__global__ void lstm_cls_kernel(
    const float* __restrict__ x,
    const float* __restrict__ Wih1, const float* __restrict__ Whh1,
    const float* __restrict__ bih1, const float* __restrict__ bhh1,
    const float* __restrict__ Wih2, const float* __restrict__ Whh2,
    const float* __restrict__ bih2, const float* __restrict__ bhh2,
    const float* __restrict__ W1, const float* __restrict__ b1,
    const float* __restrict__ W2, const float* __restrict__ b2,
    float* __restrict__ out,
    float* __restrict__ h1buf,    // [NPART][2][PB][HH1]  (sample-major rows!)
    float* __restrict__ h2buf,    // [NPART][2][PB][HH2]
    unsigned* __restrict__ ctrbase) {

  extern __shared__ float smem[];

  const int tid  = threadIdx.x;
  const int w    = tid >> 6;          // wave 0..15 = this wave's unit slot
  const int lane = tid & 63;
  const int s    = lane & 31;         // sample within partition
  const int p    = lane >> 5;         // gate-pair: 0 -> (i,f), 1 -> (g,o)
  const int part = blockIdx.x & 7;
  const int rid  = blockIdx.x >> 3;   // role 0..23
  unsigned* ctr  = ctrbase + part * 64;
  unsigned* flag = ctrbase + part * 64 + 32;

  float* h1part = h1buf + (size_t)part * 2 * PB * HH1;   // 16384 floats
  float* h2part = h2buf + (size_t)part * 2 * PB * HH2;   // 8192 floats

  if (rid < 16) {
    // ============ LSTM1 block: 16 units, unit j = rid*16 + w ============
    float* sW  = smem + L1_W;    // row r = w*4 + p*2 + gg -> (unit rid*16+(r>>2), gate r&3)
    float* sOP = smem + L1_OP;   // [32 s][324] : 0..64 x, 64..320 h1
    float* sB  = smem + L1_B;
    const int j = rid * 16 + w;

    for (int idx = tid; idx < 64 * 324; idx += NTHR) {
      int r = idx / 324, k = idx - r * 324;
      float v = 0.f;
      if (k < 320) {
        int rg = (r & 3) * HH1 + (rid * 16 + (r >> 2));
        v = (k < FF) ? Wih1[rg * FF + k] : Whh1[rg * HH1 + (k - FF)];
      }
      sW[idx] = v;
    }
    if (tid < 64) {
      int rg = (tid & 3) * HH1 + (rid * 16 + (tid >> 2));
      sB[tid] = bih1[rg] + bhh1[rg];
    }
    __syncthreads();

    const int wr0 = (w * 4 + p * 2) * 324;
    const int wr1 = wr0 + 324;
    const int ob  = s * 324;
    float c = 0.f;

    for (int i = 0; i <= TT; ++i) {
      if (i < TT) {
        const float* h1p = h1part + ((i + 1) & 1) * (PB * HH1);
        float4 g0, g1, xg;
        {
          int t1 = tid + 1024;
          cld4(g0, h1p + (tid >> 6) * HH1 + (tid & 63) * 4);
          cld4(g1, h1p + (t1 >> 6) * HH1 + (t1 & 63) * 4);
        }
        const bool hasx = tid < 512;
        if (hasx) {
          const float* xp = x + ((size_t)(part * PB + (tid >> 4)) * TT + i) * FF
                              + (tid & 15) * 4;
          xg = *reinterpret_cast<const float4*>(xp);
        }
        vm_drain();
        {
          int t1 = tid + 1024;
          *reinterpret_cast<float4*>(&sOP[(tid >> 6) * 324 + 64 + (tid & 63) * 4]) = g0;
          *reinterpret_cast<float4*>(&sOP[(t1 >> 6) * 324 + 64 + (t1 & 63) * 4])  = g1;
          if (hasx)
            *reinterpret_cast<float4*>(&sOP[(tid >> 4) * 324 + (tid & 15) * 4]) = xg;
        }
        __syncthreads();

        float a0 = sB[w * 4 + p * 2];
        float a1 = sB[w * 4 + p * 2 + 1];
        #pragma unroll 4
        for (int kt = 0; kt < 80; ++kt) {
          const int k = kt * 4;
          float4 ov = *reinterpret_cast<const float4*>(&sOP[ob + k]);
          float4 w0 = *reinterpret_cast<const float4*>(&sW[wr0 + k]);
          float4 w1 = *reinterpret_cast<const float4*>(&sW[wr1 + k]);
          a0 = __builtin_fmaf(w0.w, ov.w, __builtin_fmaf(w0.z, ov.z,
               __builtin_fmaf(w0.y, ov.y, __builtin_fmaf(w0.x, ov.x, a0))));
          a1 = __builtin_fmaf(w1.w, ov.w, __builtin_fmaf(w1.z, ov.z,
               __builtin_fmaf(w1.y, ov.y, __builtin_fmaf(w1.x, ov.x, a1))));
        }
        // exchange gate pairs across p (lane ^ 32, same wave)
        float o0 = __shfl_xor(a0, 32, 64);
        float o1 = __shfl_xor(a1, 32, 64);
        float ipre = p ? o0 : a0;
        float fpre = p ? o1 : a1;
        float gpre = p ? a0 : o0;
        float opre = p ? a1 : o1;
        c = sigmoidf_(fpre) * c + sigmoidf_(ipre) * tanhf_(gpre);
        float h = sigmoidf_(opre) * tanhf_(c);
        float* h1w = h1part + (i & 1) * (PB * HH1);
        if (p == 0) AGST(&h1w[s * HH1 + j], h);
      }
      pbarrier(ctr, flag, (unsigned)(i + 1) * NROLE);
    }

  } else {
    // ============ LSTM2 block: 16 units, unit j = (rid-16)*16 + w; trails 1 step ==
    float* sW2 = smem + L2_W;
    float* sOP = smem + L2_OP;   // [32 s][388] : 0..256 h1, 256..384 h2
    float* sB2 = smem + L2_B;
    const int j = (rid - 16) * 16 + w;

    for (int idx = tid; idx < 64 * 388; idx += NTHR) {
      int r = idx / 388, k = idx - r * 388;
      float v = 0.f;
      if (k < 384) {
        int rg = (r & 3) * HH2 + ((rid - 16) * 16 + (r >> 2));
        v = (k < HH1) ? Wih2[rg * HH1 + k] : Whh2[rg * HH2 + (k - HH1)];
      }
      sW2[idx] = v;
    }
    if (tid < 64) {
      int rg = (tid & 3) * HH2 + ((rid - 16) * 16 + (tid >> 2));
      sB2[tid] = bih2[rg] + bhh2[rg];
    }
    __syncthreads();

    const int wr0 = (w * 4 + p * 2) * 388;
    const int wr1 = wr0 + 388;
    const int ob  = s * 388;
    float c = 0.f;

    for (int i = 0; i <= TT; ++i) {
      if (i >= 1) {
        const float* h1c = h1part + ((i - 1) & 1) * (PB * HH1);  // h1[t2]
        const float* h2p = h2part + (i & 1) * (PB * HH2);        // h2[t2-1]
        float4 g0, g1, g2;
        {
          int t1 = tid + 1024;
          cld4(g0, h1c + (tid >> 6) * HH1 + (tid & 63) * 4);
          cld4(g1, h1c + (t1 >> 6) * HH1 + (t1 & 63) * 4);
          cld4(g2, h2p + (tid >> 5) * HH2 + (tid & 31) * 4);
        }
        vm_drain();
        {
          int t1 = tid + 1024;
          *reinterpret_cast<float4*>(&sOP[(tid >> 6) * 388 + (tid & 63) * 4]) = g0;
          *reinterpret_cast<float4*>(&sOP[(t1 >> 6) * 388 + (t1 & 63) * 4])  = g1;
          *reinterpret_cast<float4*>(&sOP[(tid >> 5) * 388 + 256 + (tid & 31) * 4]) = g2;
        }
        __syncthreads();

        float a0 = sB2[w * 4 + p * 2];
        float a1 = sB2[w * 4 + p * 2 + 1];
        #pragma unroll 4
        for (int kt = 0; kt < 96; ++kt) {
          const int k = kt * 4;
          float4 ov = *reinterpret_cast<const float4*>(&sOP[ob + k]);
          float4 w0 = *reinterpret_cast<const float4*>(&sW2[wr0 + k]);
          float4 w1 = *reinterpret_cast<const float4*>(&sW2[wr1 + k]);
          a0 = __builtin_fmaf(w0.w, ov.w, __builtin_fmaf(w0.z, ov.z,
               __builtin_fmaf(w0.y, ov.y, __builtin_fmaf(w0.x, ov.x, a0))));
          a1 = __builtin_fmaf(w1.w, ov.w, __builtin_fmaf(w1.z, ov.z,
               __builtin_fmaf(w1.y, ov.y, __builtin_fmaf(w1.x, ov.x, a1))));
        }
        float o0 = __shfl_xor(a0, 32, 64);
        float o1 = __shfl_xor(a1, 32, 64);
        float ipre = p ? o0 : a0;
        float fpre = p ? o1 : a1;
        float gpre = p ? a0 : o0;
        float opre = p ? a1 : o1;
        c = sigmoidf_(fpre) * c + sigmoidf_(ipre) * tanhf_(gpre);
        float h = sigmoidf_(opre) * tanhf_(c);
        float* h2w = h2part + ((i - 1) & 1) * (PB * HH2);
        if (p == 0) AGST(&h2w[s * HH2 + j], h);
      }
      pbarrier(ctr, flag, (unsigned)(i + 1) * NROLE);
    }

    if (rid == 16) {
      // ===== MLP head for this partition's 32 samples =====
      const float* hf = h2part + ((TT - 1) & 1) * (PB * HH2);  // h2[T-1], [s][128]
      float4 hv;
      cld4(hv, hf + (tid >> 5) * HH2 + (tid & 31) * 4);
      vm_drain();
      __syncthreads();                 // everyone past the loop; LDS reusable
      float* Z0 = smem;                // [32][132]
      float* Z1 = smem + 4224;         // [128][33]
      *reinterpret_cast<float4*>(&Z0[(tid >> 5) * 132 + (tid & 31) * 4]) = hv;
      __syncthreads();

      {
        const int ss = tid & 31;
        const int dg = tid >> 5;       // 0..31, 4 d's each
        #pragma unroll
        for (int dd = 0; dd < 4; ++dd) {
          int d = dg * 4 + dd;
          float a = b1[d];
          for (int k4 = 0; k4 < 32; ++k4) {
            float4 wv = *reinterpret_cast<const float4*>(&W1[d * HH2 + k4 * 4]);
            float4 h4 = *reinterpret_cast<const float4*>(&Z0[ss * 132 + k4 * 4]);
            a = __builtin_fmaf(wv.w, h4.w, __builtin_fmaf(wv.z, h4.z,
                __builtin_fmaf(wv.y, h4.y, __builtin_fmaf(wv.x, h4.x, a))));
          }
          Z1[d * 33 + ss] = fmaxf(a, 0.f);
        }
      }
      __syncthreads();
      if (tid < 32) {
        #pragma unroll
        for (int cc = 0; cc < NCLS; ++cc) {
          float a = b2[cc];
          for (int d = 0; d < DMLP; ++d)
            a = __builtin_fmaf(W2[cc * DMLP + d], Z1[d * 33 + tid], a);
          out[(size_t)(part * PB + tid) * NCLS + cc] = a;
        }
      }
    }
  }
}

extern "C" void kernel_launch(void* const* d_in, const int* in_sizes, int n_in,
                              void* d_out, int out_size, void* d_ws, size_t ws_size,
                              hipStream_t stream) {
  (void)in_sizes; (void)n_in; (void)out_size; (void)ws_size;

  const float* xx   = (const float*)d_in[0];
  const float* Wih1 = (const float*)d_in[1];
  const float* Whh1 = (const float*)d_in[2];
  const float* bih1 = (const float*)d_in[3];
  const float* bhh1 = (const float*)d_in[4];
  const float* Wih2 = (const float*)d_in[5];
  const float* Whh2 = (const float*)d_in[6];
  const float* bih2 = (const float*)d_in[7];
  const float* bhh2 = (const float*)d_in[8];
  const float* W1   = (const float*)d_in[9];
  const float* b1   = (const float*)d_in[10];
  const float* W2   = (const float*)d_in[11];
  const float* b2   = (const float*)d_in[12];

  float*    h1buf = (float*)d_ws;                          // 8*2*32*256 f32 = 512 KB
  float*    h2buf = h1buf + (size_t)NPART * 2 * PB * HH1;  // 8*2*32*128 f32 = 256 KB
  unsigned* ctr   = (unsigned*)(h2buf + (size_t)NPART * 2 * PB * HH2);

  size_t zero_bytes =
      (size_t)NPART * 2 * (HH1 + HH2) * PB * sizeof(float) +
      (size_t)NPART * 64 * sizeof(unsigned);
  hipMemsetAsync(d_ws, 0, zero_bytes, stream);   // h buffers + barrier ctrs/flags

  // Host-side property set (not a stream op) -- safe under graph capture.
  (void)hipFuncSetAttribute(reinterpret_cast<const void*>(lstm_cls_kernel),
                            hipFuncAttributeMaxDynamicSharedMemorySize,
                            SMEM_BYTES);

  hipLaunchKernelGGL(lstm_cls_kernel, dim3(NPART * NROLE), dim3(NTHR),
                     SMEM_BYTES, stream,
                     xx, Wih1, Whh1, bih1, bhh1, Wih2, Whh2, bih2, bhh2,
                     W1, b1, W2, b2, (float*)d_out, h1buf, h2buf, ctr);
}